// Round 19
// baseline (174.030 us; speedup 1.0000x reference)
//
#include <hip/hip_runtime.h>
#include <hip/hip_fp16.h>

#define EPS 1e-5f
#define NREP 16       // colsum/sumsq replicas (breaks the R8/R9 atomic storm)
#define REPSTRIDE 132 // floats per replica row; 132 % 16 = 4 staggers L2 lines
#define MAXDEG 48     // padded-CSR slots/node; deg ~ Poisson(12), P(any>48) ~ 1e-10

typedef _Float16 half8_t __attribute__((ext_vector_type(8)));
typedef float floatx4 __attribute__((ext_vector_type(4)));

// ---------------------------------------------------------------------------
// K1 (R11, FINAL): single-pass padded-CSR build. Fusion with gemm tried twice
// and permanently abandoned (R16 +34us, R18 +80us).
__global__ void scatter_kernel(const int* __restrict__ row, const int* __restrict__ col,
                               int* __restrict__ cursor, int* __restrict__ csr, int E) {
    int e = blockIdx.x * blockDim.x + threadIdx.x;
    if (e < E) {
        int c = col[e];
        int pos = atomicAdd(&cursor[c], 1);
        if (pos < MAXDEG) csr[c * MAXDEG + pos] = row[e];  // guard unreachable in practice
    }
}

// ---------------------------------------------------------------------------
// K4 (R10, FINAL): xs = fp16( (x @ W.T) * dinv[row] ) — MFMA, W staged once
// per block into padded LDS. Interleaved N*128 xsh layout. dinv node-side.
//
// Layouts (m89/m92-verified conventions):
//   A frag (16x32): lane l elem j -> A[l&15][8*(l>>4)+j]
//   B frag (32x16): lane l elem j -> B[8*(l>>4)+j][l&15]
//   D frag (16x16): lane l reg  r -> D[4*(l>>4)+r][l&15]
// LDS = fp16 W row-major, pad to 136 halves (272B stride == 4 mod 32 dwords ->
// conflict-free b128). x zero-reuse -> direct float4 + in-reg cvt.
__global__ __launch_bounds__(256) void gemm_kernel(
    const float* __restrict__ x, const float* __restrict__ W,
    const int* __restrict__ cursor, __half* __restrict__ xsh, int N) {
    __shared__ _Float16 sw[128][136];  // 34.8 KB

    int tid = threadIdx.x;
#pragma unroll
    for (int t = 0; t < 16; ++t) {
        int idx = tid + t * 256;      // [0, 4096)
        int j = idx >> 5;
        int k4 = idx & 31;
        float4 v = ((const float4*)W)[idx];
        _Float16* d = &sw[j][k4 * 4];
        d[0] = (_Float16)v.x; d[1] = (_Float16)v.y;
        d[2] = (_Float16)v.z; d[3] = (_Float16)v.w;
    }
    __syncthreads();

    int w  = tid >> 6;
    int l  = tid & 63;
    int lr = l & 15;
    int kb = l >> 4;

    int rowA = blockIdx.x * 64 + w * 16 + lr;
    const float4* xr = (const float4*)&x[(size_t)min(rowA, N - 1) * 128];

    float4 xv[8];
#pragma unroll
    for (int kk = 0; kk < 4; ++kk) {
        xv[2 * kk]     = xr[8 * kk + 2 * kb];
        xv[2 * kk + 1] = xr[8 * kk + 2 * kb + 1];
    }
    half8_t a[4];
#pragma unroll
    for (int kk = 0; kk < 4; ++kk) {
        float4 v0 = xv[2 * kk], v1 = xv[2 * kk + 1];
        half8_t h;
        h[0] = (_Float16)v0.x; h[1] = (_Float16)v0.y;
        h[2] = (_Float16)v0.z; h[3] = (_Float16)v0.w;
        h[4] = (_Float16)v1.x; h[5] = (_Float16)v1.y;
        h[6] = (_Float16)v1.z; h[7] = (_Float16)v1.w;
        a[kk] = h;
    }

    floatx4 acc[8];
#pragma unroll
    for (int t = 0; t < 8; ++t) acc[t] = (floatx4){0.f, 0.f, 0.f, 0.f};

#pragma unroll
    for (int kk = 0; kk < 4; ++kk) {
#pragma unroll
        for (int t = 0; t < 8; ++t) {
            half8_t b = *(const half8_t*)&sw[16 * t + lr][32 * kk + 8 * kb];
            acc[t] = __builtin_amdgcn_mfma_f32_16x16x32_f16(a[kk], b, acc[t], 0, 0, 0);
        }
    }

    int rbase = blockIdx.x * 64 + w * 16 + 4 * kb;
    float dv[4];
#pragma unroll
    for (int r = 0; r < 4; ++r)
        dv[r] = (rbase + r < N) ? rsqrtf((float)(cursor[rbase + r] + 1)) : 0.f;
#pragma unroll
    for (int r = 0; r < 4; ++r) {
        int grow = rbase + r;
        if (grow < N) {
#pragma unroll
            for (int t = 0; t < 8; ++t)
                xsh[(size_t)grow * 128 + 16 * t + lr] = __float2half(acc[t][r] * dv[r]);
        }
    }
}

// ---------------------------------------------------------------------------
// K5 (R20, FINAL): clamped-16 gather + depth-1 cross-iteration index prefetch
// — best measured (44.5us). Ladder: R11 52us -> R15 clamped-16 48.5us (killed
// intra-node serial tail) -> R20 44.5us (killed per-node prologue chain:
// cursor/self/index-line prefetched under previous node's gathers).
// Closed/abandoned: multi-pass slicing +100us (compulsory-miss dominated,
// R12/R13); wide-lane +13us (divergence, R14); edge-side dinv +34us
// (dependent cursor loads, R16); NT stores +4us (R17); depth-2 value
// pipeline +4us (issue overhead + coarser waitcnt, R21). Latency structure
// exhausted; ~44us is the floor for this access pattern at 2048 blocks.
__global__ void gather_kernel(const __half2* __restrict__ xs2, const int* __restrict__ cursor,
                              const int* __restrict__ csr,
                              float* __restrict__ pre, float* __restrict__ colrep,
                              float* __restrict__ ssrep, int N) {
    __shared__ float scol[128];
    __shared__ float sss;
    if (threadIdx.x < 128) scol[threadIdx.x] = 0.f;
    if (threadIdx.x == 0) sss = 0.f;
    __syncthreads();

    int lane = threadIdx.x & 63;
    int wid = (blockIdx.x * blockDim.x + threadIdx.x) >> 6;
    int nw  = (gridDim.x * blockDim.x) >> 6;
    float2* pre2 = (float2*)pre;
    float csx = 0.f, csy = 0.f, ss = 0.f;

    int n = wid;
    int pDeg = 0;
    __half2 pSelf = __half2{};
    int pIdx[16];
#pragma unroll
    for (int t = 0; t < 16; ++t) pIdx[t] = 0;
    if (n < N) {                      // prologue prefetch for the first node
        pDeg = cursor[n];
        pSelf = xs2[n * 64 + lane];
        const int* cs0 = &csr[n * MAXDEG];
#pragma unroll
        for (int t = 0; t < 16; ++t) pIdx[t] = cs0[t];
    }

    for (; n < N; n += nw) {
        int deg = pDeg;
        __half2 selfh = pSelf;
        int idx0[16];
#pragma unroll
        for (int t = 0; t < 16; ++t) idx0[t] = pIdx[t];

        // issue next node's prefetch NOW — retires under this node's gathers
        int nn = n + nw;
        if (nn < N) {
            pDeg = cursor[nn];
            pSelf = xs2[nn * 64 + lane];
            const int* ncs = &csr[nn * MAXDEG];
#pragma unroll
            for (int t = 0; t < 16; ++t) pIdx[t] = ncs[t];
        }

        int e = min(deg, MAXDEG);
        float2 acc = __half22float2(selfh);   // self loop term
        if (e > 0) {
            // batch 0 from prefetched indices (register-only select)
            __half2 a[16];
#pragma unroll
            for (int t = 0; t < 16; ++t) {
                int ix = (t < e) ? idx0[t] : idx0[0];
                a[t] = xs2[ix * 64 + lane];
            }
#pragma unroll
            for (int t = 0; t < 16; ++t) {
                float m = (t < e) ? 1.f : 0.f;
                float2 f = __half22float2(a[t]);
                acc.x += m * f.x; acc.y += m * f.y;
            }
            // batches 1+ (deg > 16, ~10% of nodes): R15 clamped path
            const int* cs = &csr[n * MAXDEG];
            for (int base = 16; base < e; base += 16) {
                int idx[16];
#pragma unroll
                for (int t = 0; t < 16; ++t) idx[t] = cs[min(base + t, e - 1)];
                __half2 b[16];
#pragma unroll
                for (int t = 0; t < 16; ++t) b[t] = xs2[idx[t] * 64 + lane];
#pragma unroll
                for (int t = 0; t < 16; ++t) {
                    float m = (base + t < e) ? 1.f : 0.f;
                    float2 f = __half22float2(b[t]);
                    acc.x += m * f.x; acc.y += m * f.y;
                }
            }
        }
        float dv = rsqrtf((float)(deg + 1));
        float vx = acc.x * dv, vy = acc.y * dv;
        pre2[n * 64 + lane] = make_float2(vx, vy);
        csx += vx; csy += vy; ss += vx * vx + vy * vy;
    }

    // block-level reduction, then one atomic per slot into replica blockIdx&15
    atomicAdd(&scol[2 * lane], csx);
    atomicAdd(&scol[2 * lane + 1], csy);
    for (int d = 32; d > 0; d >>= 1) ss += __shfl_down(ss, d);
    if (lane == 0) atomicAdd(&sss, ss);
    __syncthreads();
    int rep = blockIdx.x & (NREP - 1);
    if (threadIdx.x < 128) atomicAdd(&colrep[rep * REPSTRIDE + threadIdx.x], scol[threadIdx.x]);
    if (threadIdx.x == 128) atomicAdd(&ssrep[rep], sss);
}

// ---------------------------------------------------------------------------
// K8: FUSED params + apply.
__global__ void final_kernel(float* __restrict__ out, const float* __restrict__ colrep,
                             const float* __restrict__ ssrep, int N, int total) {
    __shared__ float sm[128];
    __shared__ float red[128];
    __shared__ float sscale;
    int t = threadIdx.x;
    if (t < 128) {
        float cs = 0.f;
#pragma unroll
        for (int r = 0; r < NREP; ++r) cs += colrep[r * REPSTRIDE + t];
        float m = cs / (float)N;
        sm[t] = m;
        red[t] = m * m;
    }
    __syncthreads();
    for (int d = 64; d > 0; d >>= 1) {
        if (t < d) red[t] += red[t + d];
        __syncthreads();
    }
    if (t == 0) {
        float sq = 0.f;
#pragma unroll
        for (int r = 0; r < NREP; ++r) sq += ssrep[r];
        float tot = sq - (float)N * red[0];  // sum (out - m)^2
        sscale = rsqrtf(EPS + tot / (float)N);
    }
    __syncthreads();
    float s = sscale;
    int tid = blockIdx.x * blockDim.x + threadIdx.x;
    int stride = gridDim.x * blockDim.x;
    for (int i = tid; i < total; i += stride) {
        float y = (out[i] - sm[i & 127]) * s;
        out[i] = y > 0.f ? 2.f * y : y;
    }
}

// ---------------------------------------------------------------------------
extern "C" void kernel_launch(void* const* d_in, const int* in_sizes, int n_in,
                              void* d_out, int out_size, void* d_ws, size_t ws_size,
                              hipStream_t stream) {
    const float* x = (const float*)d_in[0];
    const float* W = (const float*)d_in[1];
    const int* ei  = (const int*)d_in[2];
    int N = in_sizes[0] / 128;
    int E = in_sizes[2] / 2;
    const int* row = ei;        // edge_index[0] = source
    const int* col = ei + E;    // edge_index[1] = aggregation target
    float* out = (float*)d_out;

    // workspace layout: ~12.8MB (xsh) + 0.2 (cursor) + 9.6 (csr) ~= 22.8 MB
    __half* xsh      = (__half*)d_ws;                  // N*128 halves (interleaved)
    int*   cursor    = (int*)((float*)d_ws + (size_t)N * 64);  // N      [zeroed]
    float* colrep    = (float*)(cursor + N);           // NREP*REPSTRIDE [zeroed]
    float* ssrep     = colrep + NREP * REPSTRIDE;      // NREP           [zeroed]
    int*   csr       = (int*)(ssrep + NREP);           // N*MAXDEG

    hipMemsetAsync(cursor, 0, (size_t)(N + NREP * REPSTRIDE + NREP) * 4, stream);

    scatter_kernel<<<(E + 255) / 256, 256, 0, stream>>>(row, col, cursor, csr, E);
    gemm_kernel   <<<(N + 63) / 64, 256, 0, stream>>>(x, W, cursor, xsh, N);
    gather_kernel <<<2048, 256, 0, stream>>>((const __half2*)xsh, cursor, csr,
                                             out, colrep, ssrep, N);
    final_kernel  <<<1024, 256, 0, stream>>>(out, colrep, ssrep, N, N * 128);
}